// Round 5
// baseline (172.032 us; speedup 1.0000x reference)
//
#include <hip/hip_runtime.h>

// PositionDropout: out[b,s,d] = scale(b,s) * x[b,s,d]
// scale(b,s) = bernoulli(prox) / (prox + 1e-5), bernoulli = JAX threefry2x32,
// key (0,42), partitionable random_bits (bits = o0 ^ o1, counter (0, row)).
// Bit-exact vs reference (verified rounds 1-4, absmax 0.03 = f32 mul assoc).
//
// R5 changes:
//  1. Dropped-row skip: scale==0 exactly when mask==0 or padding -> out row
//     is all zeros; skip the 3 row loads (wave-uniform branch, ~55-60% of
//     rows). Cuts read traffic ~100 MB -> ~42 MB.
//  2. Loads back to temporal (x likely LLC-warm from harness restore);
//     stores stay nontemporal (R4 confirmed ~10 us win from avoiding
//     write-allocate).

static constexpr int Bn = 64, Sn = 512, Dn = 768;
static constexpr int ROWS = Bn * Sn;            // 32768 rows
static constexpr int F4_PER_ROW = Dn / 4;       // 192

typedef float vfloat4 __attribute__((ext_vector_type(4)));

__device__ __forceinline__ unsigned rotl32(unsigned x, int d) {
  return (x << d) | (x >> (32 - d));
}

// Threefry-2x32, 20 rounds, key hard-coded to (0, 42) = jax.random.key(42)
__device__ __forceinline__ void threefry2x32_0_42(unsigned x0, unsigned x1,
                                                  unsigned& o0, unsigned& o1) {
  const unsigned ks0 = 0u;
  const unsigned ks1 = 42u;
  const unsigned ks2 = 0u ^ 42u ^ 0x1BD11BDAu;
  unsigned v0 = x0 + ks0;
  unsigned v1 = x1 + ks1;
#define RG(a, b, c, d)                       \
  v0 += v1; v1 = rotl32(v1, a); v1 ^= v0;    \
  v0 += v1; v1 = rotl32(v1, b); v1 ^= v0;    \
  v0 += v1; v1 = rotl32(v1, c); v1 ^= v0;    \
  v0 += v1; v1 = rotl32(v1, d); v1 ^= v0;
  RG(13, 15, 26, 6)   v0 += ks1; v1 += ks2 + 1u;
  RG(17, 29, 16, 24)  v0 += ks2; v1 += ks0 + 2u;
  RG(13, 15, 26, 6)   v0 += ks0; v1 += ks1 + 3u;
  RG(17, 29, 16, 24)  v0 += ks1; v1 += ks2 + 4u;
  RG(13, 15, 26, 6)   v0 += ks2; v1 += ks0 + 5u;
#undef RG
  o0 = v0;
  o1 = v1;
}

// Exactly mirrors the reference's f32 op sequence so u < prox matches bitwise.
__device__ __forceinline__ float row_scale(int row,
                                           const int* __restrict__ abi,
                                           const int* __restrict__ tl,
                                           const int* __restrict__ al) {
  unsigned o0, o1;
  threefry2x32_0_42(0u, (unsigned)row, o0, o1);
  unsigned bits = o0 ^ o1;

  int b = row >> 9;          // row / Sn
  int s = row & (Sn - 1);    // row % Sn
  float jf  = (float)s;
  float b0f = (float)abi[2 * b];
  float b1f = (float)abi[2 * b + 1];
  int   tli = tl[b];
  float tlf = (float)tli;
  float ctx = (float)(tli - al[b]);   // int sub then exact cvt

  float prox;
  if (jf < b0f)       prox = 1.0f - (b0f - jf) / ctx;
  else if (jf <= b1f) prox = 1.0f / ctx;
  else                prox = 1.0f - (jf - b1f) / ctx;
  prox = (jf < tlf) ? prox : 0.0f;
  prox = fminf(fmaxf(prox, 0.0f), 1.0f);

  // JAX uniform: bitcast((bits>>9)|0x3f800000) - 1.0  in [0,1)
  float u = __uint_as_float((bits >> 9) | 0x3f800000u) - 1.0f;
  float mask = (u < prox) ? 1.0f : 0.0f;
  return mask / (prox + 1e-5f);   // == 0.0f exactly when mask == 0
}

// One wave per row. Block = 256 threads = 4 waves = 4 rows.
__global__ void __launch_bounds__(256)
pos_dropout_fused(const vfloat4* __restrict__ x,
                  const int* __restrict__ abi,
                  const int* __restrict__ tl,
                  const int* __restrict__ al,
                  vfloat4* __restrict__ out) {
  int gtid = blockIdx.x * 256 + threadIdx.x;
  int row  = gtid >> 6;          // global wave id == row, 0..ROWS-1
  int lane = gtid & 63;

  float s = row_scale(row, abi, tl, al);   // wave-uniform

  int base = row * F4_PER_ROW + lane;      // 192 float4/row, 3 per lane

  if (s == 0.0f) {
    // Dropped or padding row: output is exactly zero; skip the loads.
    vfloat4 z = {0.0f, 0.0f, 0.0f, 0.0f};
    __builtin_nontemporal_store(z, &out[base]);
    __builtin_nontemporal_store(z, &out[base + 64]);
    __builtin_nontemporal_store(z, &out[base + 128]);
    return;
  }

  vfloat4 v0 = x[base];
  vfloat4 v1 = x[base + 64];
  vfloat4 v2 = x[base + 128];
  v0 *= s;
  v1 *= s;
  v2 *= s;
  __builtin_nontemporal_store(v0, &out[base]);
  __builtin_nontemporal_store(v1, &out[base + 64]);
  __builtin_nontemporal_store(v2, &out[base + 128]);
}

extern "C" void kernel_launch(void* const* d_in, const int* in_sizes, int n_in,
                              void* d_out, int out_size, void* d_ws, size_t ws_size,
                              hipStream_t stream) {
  const float* x  = (const float*)d_in[0];
  const int* abi  = (const int*)d_in[1];   // [B,2]
  const int* tl   = (const int*)d_in[2];   // [B]
  const int* al   = (const int*)d_in[3];   // [B]
  float* out = (float*)d_out;

  // ROWS waves -> ROWS*64 threads -> ROWS/4 blocks of 256
  pos_dropout_fused<<<ROWS / 4, 256, 0, stream>>>(
      (const vfloat4*)x, abi, tl, al, (vfloat4*)out);
}

// Round 6
// 164.265 us; speedup vs baseline: 1.0473x; 1.0473x over previous
//
#include <hip/hip_runtime.h>

// PositionDropout: out[b,s,d] = scale(b,s) * x[b,s,d]
// scale(b,s) = bernoulli(prox) / (prox + 1e-5), bernoulli = JAX threefry2x32,
// key (0,42), partitionable random_bits (bits = o0 ^ o1, counter (0, row)).
// Bit-exact vs reference (verified rounds 1-5, absmax 0.03 = f32 mul assoc).
//
// R6 = R5 structure (wave-uniform zero-row skip: ~66% of rows are padding or
// bernoulli-dropped -> write zeros, skip the 3 row loads) + nontemporal loads
// in the valid path (R4's load mode; stream data, no reuse) + nontemporal
// stores (avoids L2 allocate on the 100 MB output stream).
// Traffic: ~34 MB read + ~100 MB write = ~134 MB -> ~21 us floor @ 6.3 TB/s.

static constexpr int Bn = 64, Sn = 512, Dn = 768;
static constexpr int ROWS = Bn * Sn;            // 32768 rows
static constexpr int F4_PER_ROW = Dn / 4;       // 192

typedef float vfloat4 __attribute__((ext_vector_type(4)));

__device__ __forceinline__ unsigned rotl32(unsigned x, int d) {
  return (x << d) | (x >> (32 - d));
}

// Threefry-2x32, 20 rounds, key hard-coded to (0, 42) = jax.random.key(42)
__device__ __forceinline__ void threefry2x32_0_42(unsigned x0, unsigned x1,
                                                  unsigned& o0, unsigned& o1) {
  const unsigned ks0 = 0u;
  const unsigned ks1 = 42u;
  const unsigned ks2 = 0u ^ 42u ^ 0x1BD11BDAu;
  unsigned v0 = x0 + ks0;
  unsigned v1 = x1 + ks1;
#define RG(a, b, c, d)                       \
  v0 += v1; v1 = rotl32(v1, a); v1 ^= v0;    \
  v0 += v1; v1 = rotl32(v1, b); v1 ^= v0;    \
  v0 += v1; v1 = rotl32(v1, c); v1 ^= v0;    \
  v0 += v1; v1 = rotl32(v1, d); v1 ^= v0;
  RG(13, 15, 26, 6)   v0 += ks1; v1 += ks2 + 1u;
  RG(17, 29, 16, 24)  v0 += ks2; v1 += ks0 + 2u;
  RG(13, 15, 26, 6)   v0 += ks0; v1 += ks1 + 3u;
  RG(17, 29, 16, 24)  v0 += ks1; v1 += ks2 + 4u;
  RG(13, 15, 26, 6)   v0 += ks2; v1 += ks0 + 5u;
#undef RG
  o0 = v0;
  o1 = v1;
}

// Exactly mirrors the reference's f32 op sequence so u < prox matches bitwise.
__device__ __forceinline__ float row_scale(int row,
                                           const int* __restrict__ abi,
                                           const int* __restrict__ tl,
                                           const int* __restrict__ al) {
  unsigned o0, o1;
  threefry2x32_0_42(0u, (unsigned)row, o0, o1);
  unsigned bits = o0 ^ o1;

  int b = row >> 9;          // row / Sn
  int s = row & (Sn - 1);    // row % Sn
  float jf  = (float)s;
  float b0f = (float)abi[2 * b];
  float b1f = (float)abi[2 * b + 1];
  int   tli = tl[b];
  float tlf = (float)tli;
  float ctx = (float)(tli - al[b]);   // int sub then exact cvt

  float prox;
  if (jf < b0f)       prox = 1.0f - (b0f - jf) / ctx;
  else if (jf <= b1f) prox = 1.0f / ctx;
  else                prox = 1.0f - (jf - b1f) / ctx;
  prox = (jf < tlf) ? prox : 0.0f;
  prox = fminf(fmaxf(prox, 0.0f), 1.0f);

  // JAX uniform: bitcast((bits>>9)|0x3f800000) - 1.0  in [0,1)
  float u = __uint_as_float((bits >> 9) | 0x3f800000u) - 1.0f;
  float mask = (u < prox) ? 1.0f : 0.0f;
  return mask / (prox + 1e-5f);   // == 0.0f exactly when mask == 0
}

// One wave per row. Block = 256 threads = 4 waves = 4 rows.
__global__ void __launch_bounds__(256)
pos_dropout_fused(const vfloat4* __restrict__ x,
                  const int* __restrict__ abi,
                  const int* __restrict__ tl,
                  const int* __restrict__ al,
                  vfloat4* __restrict__ out) {
  int gtid = blockIdx.x * 256 + threadIdx.x;
  int row  = gtid >> 6;          // global wave id == row, 0..ROWS-1
  int lane = gtid & 63;

  float s = row_scale(row, abi, tl, al);   // wave-uniform

  int base = row * F4_PER_ROW + lane;      // 192 float4/row, 3 per lane

  if (s == 0.0f) {
    // Dropped or padding row: output is exactly zero; skip the loads.
    vfloat4 z = {0.0f, 0.0f, 0.0f, 0.0f};
    __builtin_nontemporal_store(z, &out[base]);
    __builtin_nontemporal_store(z, &out[base + 64]);
    __builtin_nontemporal_store(z, &out[base + 128]);
    return;
  }

  vfloat4 v0 = __builtin_nontemporal_load(&x[base]);
  vfloat4 v1 = __builtin_nontemporal_load(&x[base + 64]);
  vfloat4 v2 = __builtin_nontemporal_load(&x[base + 128]);
  v0 *= s;
  v1 *= s;
  v2 *= s;
  __builtin_nontemporal_store(v0, &out[base]);
  __builtin_nontemporal_store(v1, &out[base + 64]);
  __builtin_nontemporal_store(v2, &out[base + 128]);
}

extern "C" void kernel_launch(void* const* d_in, const int* in_sizes, int n_in,
                              void* d_out, int out_size, void* d_ws, size_t ws_size,
                              hipStream_t stream) {
  const float* x  = (const float*)d_in[0];
  const int* abi  = (const int*)d_in[1];   // [B,2]
  const int* tl   = (const int*)d_in[2];   // [B]
  const int* al   = (const int*)d_in[3];   // [B]
  float* out = (float*)d_out;

  // ROWS waves -> ROWS*64 threads -> ROWS/4 blocks of 256
  pos_dropout_fused<<<ROWS / 4, 256, 0, stream>>>(
      (const vfloat4*)x, abi, tl, al, (vfloat4*)out);
}